// Round 4
// baseline (102.838 us; speedup 1.0000x reference)
//
#include <hip/hip_runtime.h>

// ChamferLoss: prediction [B,N,3] f32, target [B,M,3] f32 -> scalar f32.
// d2 = ||x||^2 + (||y||^2 - 2 x.y); per pair track min of (||y||^2 - 2 x.y),
// fold +||x||^2 and clamp into the per-chunk partial write (max(.,0) monotone,
// commutes with chunk-min). v4: inline-asm v_min3_f32 (2 min3 per 4 points)
// and immediate-offset LDS reads (4 points per pointer bump) to cut VALU
// issue count — kernel is pure VALU-issue-bound (R3: VALUBusy ~100%).

#define BLOCK 256
#define RPT   8      // rows per thread
#define MC    512    // target points per LDS chunk (8 KB)
#define NPTS  8192   // N == M
#define NCH   (NPTS / MC)   // 16 chunks
#define NB    4      // batch

__device__ __forceinline__ float min3f(float a, float b, float c) {
    float d;
    asm("v_min3_f32 %0, %1, %2, %3" : "=v"(d) : "v"(a), "v"(b), "v"(c));
    return d;
}

__global__ __launch_bounds__(BLOCK) void chamfer_min_fused(
    const float* __restrict__ pred, const float* __restrict__ targ,
    float* __restrict__ pA,          // [B, NCH, N] partial mins, dir pred->targ
    float* __restrict__ pB,          // [B, NCH, M] partial mins, dir targ->pred
    double* __restrict__ acc, unsigned int* __restrict__ counter) {
    // Zero the reduce kernel's accumulator/counter (stream order guarantees
    // this kernel completes before the reduce kernel starts).
    if (blockIdx.x == 0 && blockIdx.y == 0 && blockIdx.z == 0 && threadIdx.x == 0) {
        *acc = 0.0;
        *counter = 0u;
    }

    const int z   = blockIdx.z;       // 0..2B-1: dir = z>>2, b = z&3
    const int dir = z >> 2, b = z & (NB - 1);
    const float* X = dir ? targ : pred;
    const float* Y = dir ? pred : targ;
    float* partial = dir ? pB : pA;

    __shared__ float4 ldsY[MC];
    const int mc = blockIdx.y;

    // Stage Y chunk as (y.x, y.y, y.z, ||y||^2).
    for (int p = threadIdx.x; p < MC; p += BLOCK) {
        const float* yp = Y + ((size_t)b * NPTS + (size_t)mc * MC + p) * 3;
        float yx = yp[0], yy = yp[1], yz = yp[2];
        ldsY[p] = make_float4(yx, yy, yz, fmaf(yx, yx, fmaf(yy, yy, yz * yz)));
    }
    __syncthreads();

    const int row0 = blockIdx.x * (BLOCK * RPT);
    float qx[RPT], qy[RPT], qz[RPT], x2[RPT], best[RPT];
#pragma unroll
    for (int r = 0; r < RPT; ++r) {
        int row = row0 + r * BLOCK + threadIdx.x;
        const float* xp = X + ((size_t)b * NPTS + row) * 3;
        float px = xp[0], py = xp[1], pz = xp[2];
        qx[r] = -2.0f * px;
        qy[r] = -2.0f * py;
        qz[r] = -2.0f * pz;
        x2[r] = fmaf(px, px, fmaf(py, py, pz * pz));
        best[r] = 3.0e38f;
    }

    // Main loop: 4 points per iteration via immediate-offset ds_read_b128
    // (wave-uniform broadcast, conflict-free). Per 4 points per row:
    // 12 FMA + 2 v_min3 = 3.5 VALU instr/pair.
    const float4* yptr = ldsY;
#pragma unroll 2
    for (int m = 0; m < MC; m += 4) {
        float4 T0 = yptr[0];
        float4 T1 = yptr[1];
        float4 T2 = yptr[2];
        float4 T3 = yptr[3];
        yptr += 4;
#pragma unroll
        for (int r = 0; r < RPT; ++r) {
            float c0 = fmaf(qx[r], T0.x, fmaf(qy[r], T0.y, fmaf(qz[r], T0.z, T0.w)));
            float c1 = fmaf(qx[r], T1.x, fmaf(qy[r], T1.y, fmaf(qz[r], T1.z, T1.w)));
            float c2 = fmaf(qx[r], T2.x, fmaf(qy[r], T2.y, fmaf(qz[r], T2.z, T2.w)));
            float c3 = fmaf(qx[r], T3.x, fmaf(qy[r], T3.y, fmaf(qz[r], T3.z, T3.w)));
            best[r] = min3f(min3f(best[r], c0, c1), c2, c3);
        }
    }

    // Coalesced per-chunk partial write (clamp + ||x||^2 folded in).
#pragma unroll
    for (int r = 0; r < RPT; ++r) {
        int row = row0 + r * BLOCK + threadIdx.x;
        partial[((size_t)b * NCH + mc) * NPTS + row] = fmaxf(best[r] + x2[r], 0.0f);
    }
}

// 256 blocks x 256 threads: one row per thread; min over NCH chunk partials,
// block-sum in double, atomicAdd into acc; last block writes the scalar out.
__global__ __launch_bounds__(256) void chamfer_reduce(
    const float* __restrict__ pA, const float* __restrict__ pB,
    double* __restrict__ acc, unsigned int* __restrict__ counter,
    float* __restrict__ out) {
    const int g = blockIdx.x * 256 + threadIdx.x;   // 0 .. 2*B*NPTS-1
    const int half = NB * NPTS;                     // 32768 rows per direction
    const float* src = (g < half) ? pA : pB;
    const int gg = g & (half - 1);
    const int b = gg >> 13, r = gg & (NPTS - 1);

    float v = 3.0e38f;
#pragma unroll
    for (int c = 0; c < NCH; ++c)
        v = fminf(v, src[((size_t)b * NCH + c) * NPTS + r]);

    double d = (double)v;
    for (int off = 32; off > 0; off >>= 1) d += __shfl_down(d, off);
    __shared__ double sh[4];
    const int lane = threadIdx.x & 63, wid = threadIdx.x >> 6;
    if (lane == 0) sh[wid] = d;
    __syncthreads();

    if (threadIdx.x == 0) {
        double blocktotal = sh[0] + sh[1] + sh[2] + sh[3];
        atomicAdd(acc, blocktotal);
        __threadfence();
        unsigned int ticket = atomicAdd(counter, 1u);
        if (ticket == gridDim.x - 1) {
            __threadfence();
            double s = atomicAdd(acc, 0.0);   // coherent read of final sum
            out[0] = (float)(s / (double)(NB * NPTS));  // both dirs /32768
        }
    }
}

extern "C" void kernel_launch(void* const* d_in, const int* in_sizes, int n_in,
                              void* d_out, int out_size, void* d_ws, size_t ws_size,
                              hipStream_t stream) {
    const float* pred = (const float*)d_in[0];  // [B, N, 3]
    const float* targ = (const float*)d_in[1];  // [B, M, 3]
    float* out = (float*)d_out;

    float* pA = (float*)d_ws;                               // 2 MB
    float* pB = pA + (size_t)NB * NCH * NPTS;               // 2 MB
    double* acc = (double*)(pB + (size_t)NB * NCH * NPTS);
    unsigned int* counter = (unsigned int*)(acc + 1);

    // Both directions in one dispatch: grid.z = 2*B (dir, batch).
    dim3 g1(NPTS / (BLOCK * RPT), NCH, 2 * NB);             // (4, 16, 8) = 512 blocks
    chamfer_min_fused<<<g1, BLOCK, 0, stream>>>(pred, targ, pA, pB, acc, counter);

    const int nblk = 2 * NB * NPTS / 256;                   // 256
    chamfer_reduce<<<nblk, 256, 0, stream>>>(pA, pB, acc, counter, out);
}

// Round 5
// 99.564 us; speedup vs baseline: 1.0329x; 1.0329x over previous
//
#include <hip/hip_runtime.h>

// ChamferLoss: prediction [B,N,3] f32, target [B,M,3] f32 -> scalar f32.
// d2 = ||x||^2 + (||y||^2 - 2 x.y); per pair track min of (||y||^2 - 2 x.y),
// fold +||x||^2 and clamp into the per-chunk partial write.
// v5: packed-FP32 math. LDS holds point PAIRS as (x0,x1,y0,y1)/(z0,z1,w0,w1)
// float4s; v_pk_fma_f32 computes two candidates per instruction:
// per 4 points per row = 6 pk_fma + 2 v_min3 = 2 VALU instr/pair (vs 3.5).

#define BLOCK 256
#define RPT   8      // rows per thread
#define MC    512    // target points per LDS chunk
#define NPTS  8192   // N == M
#define NCH   (NPTS / MC)   // 16 chunks
#define NB    4      // batch

typedef float v2f __attribute__((ext_vector_type(2)));
typedef float v4f __attribute__((ext_vector_type(4)));

__device__ __forceinline__ float min3f(float a, float b, float c) {
    float d;
    asm("v_min3_f32 %0, %1, %2, %3" : "=v"(d) : "v"(a), "v"(b), "v"(c));
    return d;
}

// Packed dual-FMA: d.lo = a.lo*b.lo + c.lo ; d.hi = a.hi*b.hi + c.hi
__device__ __forceinline__ v2f pk_fma(v2f a, v2f b, v2f c) {
    v2f d;
    asm("v_pk_fma_f32 %0, %1, %2, %3" : "=v"(d) : "v"(a), "v"(b), "v"(c));
    return d;
}

__global__ __launch_bounds__(BLOCK) void chamfer_min_fused(
    const float* __restrict__ pred, const float* __restrict__ targ,
    float* __restrict__ pA,          // [B, NCH, N] partial mins, dir pred->targ
    float* __restrict__ pB,          // [B, NCH, M] partial mins, dir targ->pred
    double* __restrict__ acc, unsigned int* __restrict__ counter) {
    if (blockIdx.x == 0 && blockIdx.y == 0 && blockIdx.z == 0 && threadIdx.x == 0) {
        *acc = 0.0;            // stream order: done before reduce starts
        *counter = 0u;
    }

    const int z   = blockIdx.z;       // 0..2B-1: dir = z>>2, b = z&3
    const int dir = z >> 2, b = z & (NB - 1);
    const float* X = dir ? targ : pred;
    const float* Y = dir ? pred : targ;
    float* partial = dir ? pB : pA;

    // Pair-packed chunk: for points (2p, 2p+1):
    //   ldsA[p] = (x0, x1, y0, y1), ldsB[p] = (z0, z1, w0, w1), w = ||y||^2.
    __shared__ v4f ldsA[MC / 2];
    __shared__ v4f ldsB[MC / 2];
    const int mc = blockIdx.y;

    for (int p = threadIdx.x; p < MC / 2; p += BLOCK) {
        const float* yp = Y + ((size_t)b * NPTS + (size_t)mc * MC + 2 * p) * 3;
        float ax = yp[0], ay = yp[1], az = yp[2];
        float bx = yp[3], by = yp[4], bz = yp[5];
        float aw = fmaf(ax, ax, fmaf(ay, ay, az * az));
        float bw = fmaf(bx, bx, fmaf(by, by, bz * bz));
        ldsA[p] = (v4f){ax, bx, ay, by};
        ldsB[p] = (v4f){az, bz, aw, bw};
    }
    __syncthreads();

    const int row0 = blockIdx.x * (BLOCK * RPT);
    v2f qx[RPT], qy[RPT], qz[RPT];
    float x2[RPT], best[RPT];
#pragma unroll
    for (int r = 0; r < RPT; ++r) {
        int row = row0 + r * BLOCK + threadIdx.x;
        const float* xp = X + ((size_t)b * NPTS + row) * 3;
        float px = xp[0], py = xp[1], pz = xp[2];
        qx[r] = (v2f){-2.0f * px, -2.0f * px};
        qy[r] = (v2f){-2.0f * py, -2.0f * py};
        qz[r] = (v2f){-2.0f * pz, -2.0f * pz};
        x2[r] = fmaf(px, px, fmaf(py, py, pz * pz));
        best[r] = 3.0e38f;
    }

    // Main loop: 4 points (2 LDS pair-groups) per iteration.
    // LDS reads are wave-uniform broadcasts (conflict-free).
    // Per 4 points per row: 6 v_pk_fma_f32 + 2 v_min3_f32.
#pragma unroll 2
    for (int j = 0; j < MC / 2; j += 2) {
        v4f A0 = ldsA[j],     B0 = ldsB[j];
        v4f A1 = ldsA[j + 1], B1 = ldsB[j + 1];
        v2f x01 = __builtin_shufflevector(A0, A0, 0, 1);
        v2f y01 = __builtin_shufflevector(A0, A0, 2, 3);
        v2f z01 = __builtin_shufflevector(B0, B0, 0, 1);
        v2f w01 = __builtin_shufflevector(B0, B0, 2, 3);
        v2f x23 = __builtin_shufflevector(A1, A1, 0, 1);
        v2f y23 = __builtin_shufflevector(A1, A1, 2, 3);
        v2f z23 = __builtin_shufflevector(B1, B1, 0, 1);
        v2f w23 = __builtin_shufflevector(B1, B1, 2, 3);
#pragma unroll
        for (int r = 0; r < RPT; ++r) {
            v2f c01 = pk_fma(qx[r], x01, pk_fma(qy[r], y01, pk_fma(qz[r], z01, w01)));
            v2f c23 = pk_fma(qx[r], x23, pk_fma(qy[r], y23, pk_fma(qz[r], z23, w23)));
            best[r] = min3f(best[r], c01.x, c01.y);
            best[r] = min3f(best[r], c23.x, c23.y);
        }
    }

    // Coalesced per-chunk partial write (clamp + ||x||^2 folded in).
#pragma unroll
    for (int r = 0; r < RPT; ++r) {
        int row = row0 + r * BLOCK + threadIdx.x;
        partial[((size_t)b * NCH + mc) * NPTS + row] = fmaxf(best[r] + x2[r], 0.0f);
    }
}

// 64 blocks x 256 threads, 4 rows/thread via float4 loads: min over NCH chunk
// partials per row, sum 4 row-mins in double, atomicAdd; last block writes out.
__global__ __launch_bounds__(256) void chamfer_reduce(
    const float* __restrict__ pA, const float* __restrict__ pB,
    double* __restrict__ acc, unsigned int* __restrict__ counter,
    float* __restrict__ out) {
    const int g = blockIdx.x * 256 + threadIdx.x;   // thread id over 16384
    const int r4 = g * 4;                           // first of 4 rows
    const int half = NB * NPTS;                     // 32768 rows per direction
    const float* src = (r4 < half) ? pA : pB;
    const int gg = r4 & (half - 1);
    const int b = gg >> 13, r = gg & (NPTS - 1);

    v4f vb = (v4f){3.0e38f, 3.0e38f, 3.0e38f, 3.0e38f};
#pragma unroll
    for (int c = 0; c < NCH; ++c) {
        v4f v = *(const v4f*)(src + ((size_t)b * NCH + c) * NPTS + r);
        vb.x = fminf(vb.x, v.x);
        vb.y = fminf(vb.y, v.y);
        vb.z = fminf(vb.z, v.z);
        vb.w = fminf(vb.w, v.w);
    }

    double d = (double)vb.x + (double)vb.y + (double)vb.z + (double)vb.w;
    for (int off = 32; off > 0; off >>= 1) d += __shfl_down(d, off);
    __shared__ double sh[4];
    const int lane = threadIdx.x & 63, wid = threadIdx.x >> 6;
    if (lane == 0) sh[wid] = d;
    __syncthreads();

    if (threadIdx.x == 0) {
        double blocktotal = sh[0] + sh[1] + sh[2] + sh[3];
        atomicAdd(acc, blocktotal);
        __threadfence();
        unsigned int ticket = atomicAdd(counter, 1u);
        if (ticket == gridDim.x - 1) {
            __threadfence();
            double s = atomicAdd(acc, 0.0);   // coherent read of final sum
            out[0] = (float)(s / (double)(NB * NPTS));  // both dirs /32768
        }
    }
}

extern "C" void kernel_launch(void* const* d_in, const int* in_sizes, int n_in,
                              void* d_out, int out_size, void* d_ws, size_t ws_size,
                              hipStream_t stream) {
    const float* pred = (const float*)d_in[0];  // [B, N, 3]
    const float* targ = (const float*)d_in[1];  // [B, M, 3]
    float* out = (float*)d_out;

    float* pA = (float*)d_ws;                               // 2 MB
    float* pB = pA + (size_t)NB * NCH * NPTS;               // 2 MB
    double* acc = (double*)(pB + (size_t)NB * NCH * NPTS);
    unsigned int* counter = (unsigned int*)(acc + 1);

    // Both directions in one dispatch: grid.z = 2*B (dir, batch).
    dim3 g1(NPTS / (BLOCK * RPT), NCH, 2 * NB);             // (4, 16, 8) = 512 blocks
    chamfer_min_fused<<<g1, BLOCK, 0, stream>>>(pred, targ, pA, pB, acc, counter);

    const int nblk = (2 * NB * NPTS / 4) / 256;             // 64
    chamfer_reduce<<<nblk, 256, 0, stream>>>(pA, pB, acc, counter, out);
}